// Round 5
// baseline (592.935 us; speedup 1.0000x reference)
//
#include <hip/hip_runtime.h>

#define HIDDEN 256
#define NPTS (4*65536)          // 262144 points
#define MTILE 16                // points per workgroup
#define NWG (NPTS/MTILE)        // 16384
#define THREADS 256             // 4 waves

typedef _Float16 h8  __attribute__((ext_vector_type(8)));
typedef float    f4  __attribute__((ext_vector_type(4)));

__device__ __forceinline__ float tanh_fast(float x){
  // tanh(x) = 1 - 2/(exp2(2*log2e*x)+1); v_exp_f32 + v_rcp_f32
  float t = exp2f(x * 2.885390081777927f);
  return 1.0f - 2.0f * __builtin_amdgcn_rcpf(t + 1.0f);
}

__device__ __forceinline__ uint2 pack4(float a, float b, float c, float d){
  uint2 r;
  r.x = __builtin_bit_cast(unsigned int, __builtin_amdgcn_cvt_pkrtz(a, b));
  r.y = __builtin_bit_cast(unsigned int, __builtin_amdgcn_cvt_pkrtz(c, d));
  return r;
}

// act LDS addressing: [point][unit] fp16, 512B rows, XOR swizzle on bits 4-7
// (R3-verified). ubyte is the BYTE offset within the point's 512B row (2*unit).
__device__ __forceinline__ int act_off(int p, int ubyte){
  return p*512 + (ubyte ^ ((p & 15) << 4));
}

// Pack W[256][256] fp32 (row-major, [k][n]) into fp16 MFMA A-fragment layout:
// frag i = (ks*16 + nt)*64 + l holds W[ks*32 + (l>>4)*8 + j][nt*16 + (l&15)], j=0..7
__global__ void pack_weights(const float* __restrict__ W, _Float16* __restrict__ dst){
  int i = blockIdx.x * blockDim.x + threadIdx.x;   // 8192 threads total
  int l  = i & 63;
  int nt = (i >> 6) & 15;
  int ks = i >> 10;
  int k0 = ks*32 + ((l >> 4) << 3);
  int n  = nt*16 + (l & 15);
  h8 v;
  #pragma unroll
  for (int j = 0; j < 8; ++j) v[j] = (_Float16)W[(k0 + j)*HIDDEN + n];
  *reinterpret_cast<h8*>(dst + (size_t)i*8) = v;
}

__launch_bounds__(THREADS, 6)
__global__ void pinn_fused(const float* __restrict__ X,
                           const float* __restrict__ W1,
                           const float* __restrict__ b1,
                           const float* __restrict__ b2,
                           const float* __restrict__ b3,
                           const float* __restrict__ Wo,
                           const float* __restrict__ bo,
                           const _Float16* __restrict__ Wp,
                           float* __restrict__ out)
{
  // streams: 0 = h, 1 = dh/dx, 2 = dh/dy ; each [16 pts][256 units] fp16 = 8 KB
  __shared__ __align__(16) char actS[3*MTILE*512];   // 24 KB
  __shared__ __align__(16) float partS[MTILE*24];    // [16 p][4 Uq][6] = 1.5 KB

  const int tid = threadIdx.x;
  const int l   = tid & 63;
  const int lg  = l >> 4;       // k-group within fragment (0..3)
  const int lr  = l & 15;       // point within tile
  const int Uq  = __builtin_amdgcn_readfirstlane(tid >> 6);  // wave id = unit quarter (64 units)

  // ---------------- layer 1 (fp32, K=2) ----------------
  {
    const int pl = tid & 15;            // quarter-wave spreads points -> conflict-free writes
    const int ug = tid >> 4;            // 0..15, 16-unit chunk
    const int P  = blockIdx.x * MTILE + pl;
    const float2 xy = *reinterpret_cast<const float2*>(X + 2*P);
    #pragma unroll
    for (int c = 0; c < 4; ++c){
      const int u = ug*16 + c*4;
      const f4 w0 = *reinterpret_cast<const f4*>(W1 + u);
      const f4 w1 = *reinterpret_cast<const f4*>(W1 + HIDDEN + u);
      const f4 bb = *reinterpret_cast<const f4*>(b1 + u);
      float h[4], gx[4], gy[4];
      #pragma unroll
      for (int j = 0; j < 4; ++j){
        const float z = xy.x*w0[j] + xy.y*w1[j] + bb[j];
        const float t = tanh_fast(z);
        const float s = 1.0f - t*t;
        h[j]  = t;
        gx[j] = s * w0[j];
        gy[j] = s * w1[j];
      }
      const int off = act_off(pl, u*2);
      *reinterpret_cast<uint2*>(actS + 0*8192 + off) = pack4(h[0],h[1],h[2],h[3]);
      *reinterpret_cast<uint2*>(actS + 1*8192 + off) = pack4(gx[0],gx[1],gx[2],gx[3]);
      *reinterpret_cast<uint2*>(actS + 2*8192 + off) = pack4(gy[0],gy[1],gy[2],gy[3]);
    }
  }
  __syncthreads();

  // ---------------- layer 2 (fp16 MFMA, swapped operands) ----------------
  {
    const _Float16* WL = Wp;
    f4 acc[3][4];
    const f4 fzero = {0.f, 0.f, 0.f, 0.f};
    #pragma unroll
    for (int s = 0; s < 3; ++s)
      #pragma unroll
      for (int ut = 0; ut < 4; ++ut) acc[s][ut] = fzero;

    #pragma unroll
    for (int ks = 0; ks < 8; ++ks){
      h8 wf[4];
      #pragma unroll
      for (int ut = 0; ut < 4; ++ut)
        wf[ut] = *reinterpret_cast<const h8*>(WL + (size_t)(((ks*16 + Uq*4 + ut)*64 + l))*8);
      // fragment k = ks*32 + lg*8 + j  ->  byte = ks*64 + lg*16
      const int off = act_off(lr, ks*64 + lg*16);
      #pragma unroll
      for (int s = 0; s < 3; ++s){
        const h8 af = *reinterpret_cast<const h8*>(actS + s*8192 + off);
        #pragma unroll
        for (int ut = 0; ut < 4; ++ut)
          acc[s][ut] = __builtin_amdgcn_mfma_f32_16x16x32_f16(wf[ut], af, acc[s][ut], 0, 0, 0);
      }
    }
    __syncthreads();   // act reads done before overwrite

    #pragma unroll
    for (int ut = 0; ut < 4; ++ut){
      const int u0 = Uq*64 + ut*16 + lg*4;
      const f4 bb = *reinterpret_cast<const f4*>(b2 + u0);
      const f4 z  = acc[0][ut];
      const f4 zx = acc[1][ut];
      const f4 zy = acc[2][ut];
      float h[4], gx[4], gy[4];
      #pragma unroll
      for (int j = 0; j < 4; ++j){
        const float t = tanh_fast(z[j] + bb[j]);
        const float s = 1.0f - t*t;
        h[j]  = t;
        gx[j] = s * zx[j];
        gy[j] = s * zy[j];
      }
      const int off = act_off(lr, u0*2);
      *reinterpret_cast<uint2*>(actS + 0*8192 + off) = pack4(h[0],h[1],h[2],h[3]);
      *reinterpret_cast<uint2*>(actS + 1*8192 + off) = pack4(gx[0],gx[1],gx[2],gx[3]);
      *reinterpret_cast<uint2*>(actS + 2*8192 + off) = pack4(gy[0],gy[1],gy[2],gy[3]);
    }
    __syncthreads();
  }

  // ---------------- layer 3 (MFMA) fused with output layer ----------------
  {
    const _Float16* WL = Wp + 65536;
    f4 acc[3][4];
    const f4 fzero = {0.f, 0.f, 0.f, 0.f};
    #pragma unroll
    for (int s = 0; s < 3; ++s)
      #pragma unroll
      for (int ut = 0; ut < 4; ++ut) acc[s][ut] = fzero;

    #pragma unroll
    for (int ks = 0; ks < 8; ++ks){
      h8 wf[4];
      #pragma unroll
      for (int ut = 0; ut < 4; ++ut)
        wf[ut] = *reinterpret_cast<const h8*>(WL + (size_t)(((ks*16 + Uq*4 + ut)*64 + l))*8);
      const int off = act_off(lr, ks*64 + lg*16);
      #pragma unroll
      for (int s = 0; s < 3; ++s){
        const h8 af = *reinterpret_cast<const h8*>(actS + s*8192 + off);
        #pragma unroll
        for (int ut = 0; ut < 4; ++ut)
          acc[s][ut] = __builtin_amdgcn_mfma_f32_16x16x32_f16(wf[ut], af, acc[s][ut], 0, 0, 0);
      }
    }

    // L3 elementwise + Wo matvec entirely in registers (no LDS act write)
    float au=0.f, av=0.f, aux=0.f, avx=0.f, auy=0.f, avy=0.f;
    #pragma unroll
    for (int ut = 0; ut < 4; ++ut){
      const int u0 = Uq*64 + ut*16 + lg*4;
      const f4 bb  = *reinterpret_cast<const f4*>(b3 + u0);
      const f4 wo0 = *reinterpret_cast<const f4*>(Wo + 2*u0);      // rows u0, u0+1
      const f4 wo1 = *reinterpret_cast<const f4*>(Wo + 2*u0 + 4);  // rows u0+2, u0+3
      const f4 z  = acc[0][ut];
      const f4 zx = acc[1][ut];
      const f4 zy = acc[2][ut];
      #pragma unroll
      for (int j = 0; j < 4; ++j){
        const float t = tanh_fast(z[j] + bb[j]);
        const float s = 1.0f - t*t;
        const float gx = s * zx[j];
        const float gy = s * zy[j];
        const float wx = (j < 2) ? wo0[2*(j&1)]   : wo1[2*(j&1)];
        const float wy = (j < 2) ? wo0[2*(j&1)+1] : wo1[2*(j&1)+1];
        au  += t*wx;   av  += t*wy;
        aux += gx*wx;  avx += gx*wy;
        auy += gy*wx;  avy += gy*wy;
      }
    }
    // reduce over lg (lane bits 4,5); each lane then holds sums for point lr
    #pragma unroll
    for (int m = 16; m <= 32; m <<= 1){
      au  += __shfl_xor(au,  m, 64);
      av  += __shfl_xor(av,  m, 64);
      aux += __shfl_xor(aux, m, 64);
      avx += __shfl_xor(avx, m, 64);
      auy += __shfl_xor(auy, m, 64);
      avy += __shfl_xor(avy, m, 64);
    }
    if (lg == 0){
      float* pp = partS + lr*24 + Uq*6;
      *reinterpret_cast<float2*>(pp + 0) = float2{au,  av };
      *reinterpret_cast<float2*>(pp + 2) = float2{aux, avx};
      *reinterpret_cast<float2*>(pp + 4) = float2{auy, avy};
    }
  }
  __syncthreads();

  // ---------------- final: sum Uq partials + stress math ----------------
  if (tid < MTILE){
    const int p = tid;
    const int P = blockIdx.x * MTILE + p;
    float au=0.f, av=0.f, aux=0.f, avx=0.f, auy=0.f, avy=0.f;
    #pragma unroll
    for (int q = 0; q < 4; ++q){
      const float* pp = partS + p*24 + q*6;
      const float2 a = *reinterpret_cast<const float2*>(pp + 0);
      const float2 b = *reinterpret_cast<const float2*>(pp + 2);
      const float2 c = *reinterpret_cast<const float2*>(pp + 4);
      au += a.x; av += a.y; aux += b.x; avx += b.y; auy += c.x; avy += c.y;
    }
    const float C11 = 1.0989010989010988f;   // E/(1-nu^2)
    const float C12 = 0.32967032967032966f;  // E*nu/(1-nu^2)
    const float C33 = 0.38461538461538464f;  // E/(2(1+nu))
    const float u  = au + bo[0];
    const float v  = av + bo[1];
    const float uxy = auy + avx;
    const float sx  = C11*aux + C12*avy;
    const float sy  = C12*aux + C11*avy;
    const float sxy = C33*uxy;
    const float sed = 0.5f*(sx*aux + sy*avy + sxy*uxy);
    out[0*NPTS + P] = u;
    out[1*NPTS + P] = v;
    out[2*NPTS + P] = sx;
    out[3*NPTS + P] = sy;
    out[4*NPTS + P] = sxy;
    out[5*NPTS + P] = sed;
  }
}

extern "C" void kernel_launch(void* const* d_in, const int* in_sizes, int n_in,
                              void* d_out, int out_size, void* d_ws, size_t ws_size,
                              hipStream_t stream)
{
  const float* X  = (const float*)d_in[0];
  const float* W1 = (const float*)d_in[1];
  const float* b1 = (const float*)d_in[2];
  const float* W2 = (const float*)d_in[3];
  const float* b2 = (const float*)d_in[4];
  const float* W3 = (const float*)d_in[5];
  const float* b3 = (const float*)d_in[6];
  const float* Wo = (const float*)d_in[7];
  const float* bo = (const float*)d_in[8];

  _Float16* Wp = (_Float16*)d_ws;   // [2][65536] fp16 = 256 KB

  pack_weights<<<32, 256, 0, stream>>>(W2, Wp);
  pack_weights<<<32, 256, 0, stream>>>(W3, Wp + 65536);
  pinn_fused<<<NWG, THREADS, 0, stream>>>(X, W1, b1, b2, b3, Wo, bo, Wp, (float*)d_out);
}

// Round 6
// 278.819 us; speedup vs baseline: 2.1266x; 2.1266x over previous
//
#include <hip/hip_runtime.h>

#define HIDDEN 256
#define NPTS (4*65536)          // 262144 points
#define MTILE 16                // points per workgroup
#define NWG (NPTS/MTILE)        // 16384
#define THREADS 256             // 4 waves

typedef _Float16 h8  __attribute__((ext_vector_type(8)));
typedef float    f4  __attribute__((ext_vector_type(4)));

__device__ __forceinline__ float tanh_fast(float x){
  // tanh(x) = 1 - 2/(exp2(2*log2e*x)+1); v_exp_f32 + v_rcp_f32
  float t = exp2f(x * 2.885390081777927f);
  return 1.0f - 2.0f * __builtin_amdgcn_rcpf(t + 1.0f);
}

__device__ __forceinline__ uint2 pack4(float a, float b, float c, float d){
  uint2 r;
  r.x = __builtin_bit_cast(unsigned int, __builtin_amdgcn_cvt_pkrtz(a, b));
  r.y = __builtin_bit_cast(unsigned int, __builtin_amdgcn_cvt_pkrtz(c, d));
  return r;
}

// act LDS addressing: [point][unit] fp16, 512B rows, XOR swizzle on bits 4-7
// (R3-verified). ubyte is the BYTE offset within the point's 512B row (2*unit).
__device__ __forceinline__ int act_off(int p, int ubyte){
  return p*512 + (ubyte ^ ((p & 15) << 4));
}

// Pack W[256][256] fp32 (row-major, [k][n]) into fp16 MFMA A-fragment layout:
// frag i = (ks*16 + nt)*64 + l holds W[ks*32 + (l>>4)*8 + j][nt*16 + (l&15)], j=0..7
__global__ void pack_weights(const float* __restrict__ W, _Float16* __restrict__ dst){
  int i = blockIdx.x * blockDim.x + threadIdx.x;   // 8192 threads total
  int l  = i & 63;
  int nt = (i >> 6) & 15;
  int ks = i >> 10;
  int k0 = ks*32 + ((l >> 4) << 3);
  int n  = nt*16 + (l & 15);
  h8 v;
  #pragma unroll
  for (int j = 0; j < 8; ++j) v[j] = (_Float16)W[(k0 + j)*HIDDEN + n];
  *reinterpret_cast<h8*>(dst + (size_t)i*8) = v;
}

__launch_bounds__(THREADS, 2)   // empirical: VGPR cap = 256/w; w=2 -> 128 regs (body needs ~104)
__global__ void pinn_fused(const float* __restrict__ X,
                           const float* __restrict__ W1,
                           const float* __restrict__ b1,
                           const float* __restrict__ b2,
                           const float* __restrict__ b3,
                           const float* __restrict__ Wo,
                           const float* __restrict__ bo,
                           const _Float16* __restrict__ Wp,
                           float* __restrict__ out)
{
  // streams: 0 = h, 1 = dh/dx, 2 = dh/dy ; each [16 pts][256 units] fp16 = 8 KB
  __shared__ __align__(16) char actS[3*MTILE*512];   // 24 KB
  __shared__ __align__(16) float partS[MTILE*24];    // [16 p][4 Uq][6] = 1.5 KB

  const int tid = threadIdx.x;
  const int l   = tid & 63;
  const int lg  = l >> 4;       // k-group within fragment (0..3)
  const int lr  = l & 15;       // point within tile
  const int Uq  = __builtin_amdgcn_readfirstlane(tid >> 6);  // wave id = unit quarter (64 units)

  // ---------------- layer 1 (fp32, K=2) ----------------
  {
    const int pl = tid & 15;            // quarter-wave spreads points -> conflict-free writes
    const int ug = tid >> 4;            // 0..15, 16-unit chunk
    const int P  = blockIdx.x * MTILE + pl;
    const float2 xy = *reinterpret_cast<const float2*>(X + 2*P);
    #pragma unroll
    for (int c = 0; c < 4; ++c){
      const int u = ug*16 + c*4;
      const f4 w0 = *reinterpret_cast<const f4*>(W1 + u);
      const f4 w1 = *reinterpret_cast<const f4*>(W1 + HIDDEN + u);
      const f4 bb = *reinterpret_cast<const f4*>(b1 + u);
      float h[4], gx[4], gy[4];
      #pragma unroll
      for (int j = 0; j < 4; ++j){
        const float z = xy.x*w0[j] + xy.y*w1[j] + bb[j];
        const float t = tanh_fast(z);
        const float s = 1.0f - t*t;
        h[j]  = t;
        gx[j] = s * w0[j];
        gy[j] = s * w1[j];
      }
      const int off = act_off(pl, u*2);
      *reinterpret_cast<uint2*>(actS + 0*8192 + off) = pack4(h[0],h[1],h[2],h[3]);
      *reinterpret_cast<uint2*>(actS + 1*8192 + off) = pack4(gx[0],gx[1],gx[2],gx[3]);
      *reinterpret_cast<uint2*>(actS + 2*8192 + off) = pack4(gy[0],gy[1],gy[2],gy[3]);
    }
  }
  __syncthreads();

  // ---------------- layer 2 (fp16 MFMA, swapped operands) ----------------
  {
    const _Float16* WL = Wp;
    f4 acc[3][4];
    const f4 fzero = {0.f, 0.f, 0.f, 0.f};
    #pragma unroll
    for (int s = 0; s < 3; ++s)
      #pragma unroll
      for (int ut = 0; ut < 4; ++ut) acc[s][ut] = fzero;

    #pragma unroll
    for (int ks = 0; ks < 8; ++ks){
      h8 wf[4];
      #pragma unroll
      for (int ut = 0; ut < 4; ++ut)
        wf[ut] = *reinterpret_cast<const h8*>(WL + (size_t)(((ks*16 + Uq*4 + ut)*64 + l))*8);
      // fragment k = ks*32 + lg*8 + j  ->  byte = ks*64 + lg*16
      const int off = act_off(lr, ks*64 + lg*16);
      #pragma unroll
      for (int s = 0; s < 3; ++s){
        const h8 af = *reinterpret_cast<const h8*>(actS + s*8192 + off);
        #pragma unroll
        for (int ut = 0; ut < 4; ++ut)
          acc[s][ut] = __builtin_amdgcn_mfma_f32_16x16x32_f16(wf[ut], af, acc[s][ut], 0, 0, 0);
      }
    }
    __syncthreads();   // act reads done before overwrite

    #pragma unroll
    for (int ut = 0; ut < 4; ++ut){
      const int u0 = Uq*64 + ut*16 + lg*4;
      const f4 bb = *reinterpret_cast<const f4*>(b2 + u0);
      const f4 z  = acc[0][ut];
      const f4 zx = acc[1][ut];
      const f4 zy = acc[2][ut];
      float h[4], gx[4], gy[4];
      #pragma unroll
      for (int j = 0; j < 4; ++j){
        const float t = tanh_fast(z[j] + bb[j]);
        const float s = 1.0f - t*t;
        h[j]  = t;
        gx[j] = s * zx[j];
        gy[j] = s * zy[j];
      }
      const int off = act_off(lr, u0*2);
      *reinterpret_cast<uint2*>(actS + 0*8192 + off) = pack4(h[0],h[1],h[2],h[3]);
      *reinterpret_cast<uint2*>(actS + 1*8192 + off) = pack4(gx[0],gx[1],gx[2],gx[3]);
      *reinterpret_cast<uint2*>(actS + 2*8192 + off) = pack4(gy[0],gy[1],gy[2],gy[3]);
    }
    __syncthreads();
  }

  // ---------------- layer 3 (MFMA) fused with output layer ----------------
  {
    const _Float16* WL = Wp + 65536;
    f4 acc[3][4];
    const f4 fzero = {0.f, 0.f, 0.f, 0.f};
    #pragma unroll
    for (int s = 0; s < 3; ++s)
      #pragma unroll
      for (int ut = 0; ut < 4; ++ut) acc[s][ut] = fzero;

    #pragma unroll
    for (int ks = 0; ks < 8; ++ks){
      h8 wf[4];
      #pragma unroll
      for (int ut = 0; ut < 4; ++ut)
        wf[ut] = *reinterpret_cast<const h8*>(WL + (size_t)(((ks*16 + Uq*4 + ut)*64 + l))*8);
      const int off = act_off(lr, ks*64 + lg*16);
      #pragma unroll
      for (int s = 0; s < 3; ++s){
        const h8 af = *reinterpret_cast<const h8*>(actS + s*8192 + off);
        #pragma unroll
        for (int ut = 0; ut < 4; ++ut)
          acc[s][ut] = __builtin_amdgcn_mfma_f32_16x16x32_f16(wf[ut], af, acc[s][ut], 0, 0, 0);
      }
    }

    // L3 elementwise + Wo matvec entirely in registers (no LDS act write)
    float au=0.f, av=0.f, aux=0.f, avx=0.f, auy=0.f, avy=0.f;
    #pragma unroll
    for (int ut = 0; ut < 4; ++ut){
      const int u0 = Uq*64 + ut*16 + lg*4;
      const f4 bb  = *reinterpret_cast<const f4*>(b3 + u0);
      const f4 wo0 = *reinterpret_cast<const f4*>(Wo + 2*u0);      // rows u0, u0+1
      const f4 wo1 = *reinterpret_cast<const f4*>(Wo + 2*u0 + 4);  // rows u0+2, u0+3
      const f4 z  = acc[0][ut];
      const f4 zx = acc[1][ut];
      const f4 zy = acc[2][ut];
      #pragma unroll
      for (int j = 0; j < 4; ++j){
        const float t = tanh_fast(z[j] + bb[j]);
        const float s = 1.0f - t*t;
        const float gx = s * zx[j];
        const float gy = s * zy[j];
        const float wx = (j < 2) ? wo0[2*(j&1)]   : wo1[2*(j&1)];
        const float wy = (j < 2) ? wo0[2*(j&1)+1] : wo1[2*(j&1)+1];
        au  += t*wx;   av  += t*wy;
        aux += gx*wx;  avx += gx*wy;
        auy += gy*wx;  avy += gy*wy;
      }
    }
    // reduce over lg (lane bits 4,5); each lane then holds sums for point lr
    #pragma unroll
    for (int m = 16; m <= 32; m <<= 1){
      au  += __shfl_xor(au,  m, 64);
      av  += __shfl_xor(av,  m, 64);
      aux += __shfl_xor(aux, m, 64);
      avx += __shfl_xor(avx, m, 64);
      auy += __shfl_xor(auy, m, 64);
      avy += __shfl_xor(avy, m, 64);
    }
    if (lg == 0){
      float* pp = partS + lr*24 + Uq*6;
      *reinterpret_cast<float2*>(pp + 0) = float2{au,  av };
      *reinterpret_cast<float2*>(pp + 2) = float2{aux, avx};
      *reinterpret_cast<float2*>(pp + 4) = float2{auy, avy};
    }
  }
  __syncthreads();

  // ---------------- final: sum Uq partials + stress math ----------------
  if (tid < MTILE){
    const int p = tid;
    const int P = blockIdx.x * MTILE + p;
    float au=0.f, av=0.f, aux=0.f, avx=0.f, auy=0.f, avy=0.f;
    #pragma unroll
    for (int q = 0; q < 4; ++q){
      const float* pp = partS + p*24 + q*6;
      const float2 a = *reinterpret_cast<const float2*>(pp + 0);
      const float2 b = *reinterpret_cast<const float2*>(pp + 2);
      const float2 c = *reinterpret_cast<const float2*>(pp + 4);
      au += a.x; av += a.y; aux += b.x; avx += b.y; auy += c.x; avy += c.y;
    }
    const float C11 = 1.0989010989010988f;   // E/(1-nu^2)
    const float C12 = 0.32967032967032966f;  // E*nu/(1-nu^2)
    const float C33 = 0.38461538461538464f;  // E/(2(1+nu))
    const float u  = au + bo[0];
    const float v  = av + bo[1];
    const float uxy = auy + avx;
    const float sx  = C11*aux + C12*avy;
    const float sy  = C12*aux + C11*avy;
    const float sxy = C33*uxy;
    const float sed = 0.5f*(sx*aux + sy*avy + sxy*uxy);
    out[0*NPTS + P] = u;
    out[1*NPTS + P] = v;
    out[2*NPTS + P] = sx;
    out[3*NPTS + P] = sy;
    out[4*NPTS + P] = sxy;
    out[5*NPTS + P] = sed;
  }
}

extern "C" void kernel_launch(void* const* d_in, const int* in_sizes, int n_in,
                              void* d_out, int out_size, void* d_ws, size_t ws_size,
                              hipStream_t stream)
{
  const float* X  = (const float*)d_in[0];
  const float* W1 = (const float*)d_in[1];
  const float* b1 = (const float*)d_in[2];
  const float* W2 = (const float*)d_in[3];
  const float* b2 = (const float*)d_in[4];
  const float* W3 = (const float*)d_in[5];
  const float* b3 = (const float*)d_in[6];
  const float* Wo = (const float*)d_in[7];
  const float* bo = (const float*)d_in[8];

  _Float16* Wp = (_Float16*)d_ws;   // [2][65536] fp16 = 256 KB

  pack_weights<<<32, 256, 0, stream>>>(W2, Wp);
  pack_weights<<<32, 256, 0, stream>>>(W3, Wp + 65536);
  pinn_fused<<<NWG, THREADS, 0, stream>>>(X, W1, b1, b2, b3, Wo, bo, Wp, (float*)d_out);
}